// Round 1
// baseline (481.458 us; speedup 1.0000x reference)
//
#include <hip/hip_runtime.h>
#include <hip/hip_bf16.h>

// Problem constants (fixed by the reference)
#define NTOK 4096
#define HID  512
#define EMB  512
#define INSZ 1024   // E + H = 1024 ... wait, IN = E + H = 512+512 = 1024
#define KCAT 64
#define CCH  128
#define MCELL 4
#define G4H  2048   // 4*H

typedef __bf16 bf16x8 __attribute__((ext_vector_type(8)));
typedef float  f32x4  __attribute__((ext_vector_type(4)));

__device__ inline unsigned short f2bf(float f) {
    unsigned u = __float_as_uint(f);
    u += 0x7fffu + ((u >> 16) & 1u);   // RTNE
    return (unsigned short)(u >> 16);
}

__device__ inline void store_bf4(unsigned short* p, float4 v) {
    ushort4 r;
    r.x = f2bf(v.x); r.y = f2bf(v.y); r.z = f2bf(v.z); r.w = f2bf(v.w);
    *reinterpret_cast<ushort4*>(p) = r;
}

// ---------------------------------------------------------------------------
// Kernel 1: bucket tokens by child_index (M=4). meta: [0..3]=cnt, [4..7]=off
// ---------------------------------------------------------------------------
__global__ __launch_bounds__(1024) void build_perm(const int* __restrict__ ci,
                                                   int* __restrict__ meta,
                                                   int* __restrict__ perm) {
    __shared__ int scnt[MCELL];
    __shared__ int scur[MCELL];
    int tid = threadIdx.x;
    int lane = tid & 63;
    if (tid < MCELL) scnt[tid] = 0;
    __syncthreads();
    for (int t = tid; t < NTOK; t += 1024) {
        int m = ci[t];
        #pragma unroll
        for (int mm = 0; mm < MCELL; ++mm) {
            unsigned long long mask = __ballot(m == mm);
            if (lane == 0 && mask) atomicAdd(&scnt[mm], __popcll(mask));
        }
    }
    __syncthreads();
    if (tid == 0) {
        int off = 0;
        #pragma unroll
        for (int mm = 0; mm < MCELL; ++mm) {
            meta[mm] = scnt[mm];
            meta[4 + mm] = off;
            scur[mm] = off;
            off += scnt[mm];
        }
    }
    __syncthreads();
    for (int t = tid; t < NTOK; t += 1024) {
        int m = ci[t];
        #pragma unroll
        for (int mm = 0; mm < MCELL; ++mm) {
            unsigned long long mask = __ballot(m == mm);
            int cntm = __popcll(mask);
            int base = 0;
            if (lane == 0 && cntm) base = atomicAdd(&scur[mm], cntm);
            base = __shfl(base, 0);
            if (m == mm) {
                int rank = __popcll(mask & ((1ull << lane) - 1ull));
                perm[base + rank] = t;
            }
        }
    }
}

// ---------------------------------------------------------------------------
// Kernel 2: routed-LSTM gates GEMM. Per bucket m: A=[cnt x 1536] (x|h rows,
// permuted), B=W rows [2048 x 1536] (W_ih|W_hh), C=gates [slot x 2048] f32.
// bf16 MFMA 16x16x32, 128x128 tile, BK=32, f32->bf16 convert in staging.
// ---------------------------------------------------------------------------
#define BM 128
#define BN 128
#define BK 32
#define LDT 48   // LDS row stride in bf16 elems (32 + 16 pad, keeps 16B align)

__global__ __launch_bounds__(256) void gates_gemm(
    const float* __restrict__ x,     // [N,1024]
    const float* __restrict__ h,     // [N,512]
    const float* __restrict__ Wih,   // [4,2048,1024]
    const float* __restrict__ Whh,   // [4,2048,512]
    const int*  __restrict__ meta,
    const int*  __restrict__ perm,
    float* __restrict__ gates)       // [N,2048] in perm (slot) order
{
    int rt = blockIdx.x;   // row tile within bucket
    int ct = blockIdx.y;   // col (gate) tile, 0..15
    int m  = blockIdx.z;   // bucket
    int cnt = meta[m];
    if (rt * BM >= cnt) return;
    int off = meta[4 + m];

    __shared__ unsigned short As[BM * LDT];
    __shared__ unsigned short Bs[BN * LDT];
    __shared__ int srow[BM];

    int tid = threadIdx.x;
    if (tid < BM) {
        int ridx = rt * BM + tid;
        srow[tid] = perm[off + (ridx < cnt ? ridx : 0)];
    }
    __syncthreads();

    const int lane = tid & 63;
    const int wave = tid >> 6;
    const int wr = wave >> 1;   // 0..1
    const int wc = wave & 1;    // 0..1
    const int qd = lane >> 4;   // 0..3
    const int l15 = lane & 15;

    f32x4 acc[4][4];
    #pragma unroll
    for (int i = 0; i < 4; ++i)
        #pragma unroll
        for (int j = 0; j < 4; ++j)
            acc[i][j] = (f32x4){0.f, 0.f, 0.f, 0.f};

    const size_t wih_base = ((size_t)m * G4H + (size_t)ct * BN) * (size_t)INSZ;
    const size_t whh_base = ((size_t)m * G4H + (size_t)ct * BN) * (size_t)HID;

    for (int kk = 0; kk < 1536; kk += BK) {
        const bool inx = (kk < INSZ);  // whole BK-step lies in x or in h
        #pragma unroll
        for (int it = 0; it < 4; ++it) {
            int idx = tid + it * 256;          // 0..1023
            int r = idx >> 3;                  // 0..127
            int colg = (idx & 7) * 4;          // 0,4,...,28
            // A tile: token rows
            int t = srow[r];
            const float* asrc = inx ? (x + (size_t)t * INSZ + kk + colg)
                                    : (h + (size_t)t * HID + (kk - INSZ) + colg);
            float4 av = *(const float4*)asrc;
            store_bf4(&As[r * LDT + colg], av);
            // B tile: weight rows (gate g = ct*BN + r)
            const float* bsrc = inx ? (Wih + wih_base + (size_t)r * INSZ + kk + colg)
                                    : (Whh + whh_base + (size_t)r * HID + (kk - INSZ) + colg);
            float4 bv = *(const float4*)bsrc;
            store_bf4(&Bs[r * LDT + colg], bv);
        }
        __syncthreads();

        bf16x8 fa[4], fb[4];
        #pragma unroll
        for (int ti = 0; ti < 4; ++ti)
            fa[ti] = *reinterpret_cast<const bf16x8*>(&As[(wr * 64 + ti * 16 + l15) * LDT + qd * 8]);
        #pragma unroll
        for (int tj = 0; tj < 4; ++tj)
            fb[tj] = *reinterpret_cast<const bf16x8*>(&Bs[(wc * 64 + tj * 16 + l15) * LDT + qd * 8]);
        #pragma unroll
        for (int ti = 0; ti < 4; ++ti)
            #pragma unroll
            for (int tj = 0; tj < 4; ++tj)
                acc[ti][tj] = __builtin_amdgcn_mfma_f32_16x16x32_bf16(fa[ti], fb[tj], acc[ti][tj], 0, 0, 0);
        __syncthreads();
    }

    // Store C in slot order (coalesced), masked at bucket tail.
    int rowrem = cnt - rt * BM;   // >0 here
    #pragma unroll
    for (int ti = 0; ti < 4; ++ti) {
        int lr0 = wr * 64 + ti * 16 + qd * 4;
        #pragma unroll
        for (int tj = 0; tj < 4; ++tj) {
            int gcol = ct * BN + wc * 64 + tj * 16 + l15;
            #pragma unroll
            for (int r = 0; r < 4; ++r) {
                int lr = lr0 + r;
                if (lr < rowrem) {
                    gates[(size_t)(off + rt * BM + lr) * G4H + gcol] = acc[ti][tj][r];
                }
            }
        }
    }
}

// ---------------------------------------------------------------------------
// Kernel 3: log_odds — block per token, wave per 32 outputs, f32 exact.
// ---------------------------------------------------------------------------
__global__ __launch_bounds__(256) void logodds_kernel(
    const float* __restrict__ et,    // [N,512]
    const int*  __restrict__ cat,    // [N]
    const float* __restrict__ W_lin, // [64,128,512]
    const float* __restrict__ b_lin, // [64,128]
    float* __restrict__ out)         // log_odds at out[0 .. N*128)
{
    int t = blockIdx.x;
    int k = cat[t];
    int tid = threadIdx.x;
    int lane = tid & 63;
    int wave = tid >> 6;

    const float* e = et + (size_t)t * HID;
    float4 e0 = *(const float4*)(e + lane * 4);
    float4 e1 = *(const float4*)(e + 256 + lane * 4);

    const float* Wb = W_lin + (size_t)k * CCH * HID;
    #pragma unroll 4
    for (int j = 0; j < 32; ++j) {
        int cc = wave * 32 + j;
        const float* wrow = Wb + (size_t)cc * HID;
        float4 w0 = *(const float4*)(wrow + lane * 4);
        float4 w1 = *(const float4*)(wrow + 256 + lane * 4);
        float s = e0.x * w0.x + e0.y * w0.y + e0.z * w0.z + e0.w * w0.w
                + e1.x * w1.x + e1.y * w1.y + e1.z * w1.z + e1.w * w1.w;
        #pragma unroll
        for (int o = 32; o > 0; o >>= 1) s += __shfl_xor(s, o);
        if (lane == 0) out[(size_t)t * CCH + cc] = s + b_lin[k * CCH + cc];
    }
}

// ---------------------------------------------------------------------------
// Kernel 4: LSTM pointwise epilogue. slot -> token via perm; bucket via off.
// ---------------------------------------------------------------------------
__global__ __launch_bounds__(256) void lstm_epilogue(
    const float* __restrict__ gates,  // [N,2048] slot order
    const int*  __restrict__ meta,
    const int*  __restrict__ perm,
    const float* __restrict__ c,      // [N,512]
    const float* __restrict__ b_ih,   // [4,2048]
    const float* __restrict__ b_hh,   // [4,2048]
    float* __restrict__ out)          // h2 at N*128, c2 at N*128 + N*512
{
    int idx = blockIdx.x * 256 + threadIdx.x;   // [0, N*512)
    int s = idx >> 9;        // slot
    int hh = idx & 511;
    int off1 = meta[5], off2 = meta[6], off3 = meta[7];
    int m = (s >= off1) + (s >= off2) + (s >= off3);
    int t = perm[s];

    const float* g = gates + (size_t)s * G4H;
    const float* bi = b_ih + (size_t)m * G4H;
    const float* bh = b_hh + (size_t)m * G4H;
    float gi = g[hh]        + bi[hh]        + bh[hh];
    float gf = g[512 + hh]  + bi[512 + hh]  + bh[512 + hh];
    float gg = g[1024 + hh] + bi[1024 + hh] + bh[1024 + hh];
    float go = g[1536 + hh] + bi[1536 + hh] + bh[1536 + hh];

    float si = 1.f / (1.f + __expf(-gi));
    float sf = 1.f / (1.f + __expf(-gf));
    float so = 1.f / (1.f + __expf(-go));
    float ct = c[(size_t)t * HID + hh];
    float c2 = sf * ct + si * tanhf(gg);
    float h2 = so * tanhf(c2);

    const size_t o_h2 = (size_t)NTOK * CCH;
    const size_t o_c2 = o_h2 + (size_t)NTOK * HID;
    out[o_h2 + (size_t)t * HID + hh] = h2;
    out[o_c2 + (size_t)t * HID + hh] = c2;
}

// ---------------------------------------------------------------------------
extern "C" void kernel_launch(void* const* d_in, const int* in_sizes, int n_in,
                              void* d_out, int out_size, void* d_ws, size_t ws_size,
                              hipStream_t stream) {
    const float* et    = (const float*)d_in[0];
    const float* x     = (const float*)d_in[1];
    const float* h     = (const float*)d_in[2];
    const float* c     = (const float*)d_in[3];
    const int*   cat   = (const int*)d_in[4];
    const int*   ci    = (const int*)d_in[5];
    const float* W_lin = (const float*)d_in[6];
    const float* b_lin = (const float*)d_in[7];
    const float* W_ih  = (const float*)d_in[8];
    const float* W_hh  = (const float*)d_in[9];
    const float* b_ih  = (const float*)d_in[10];
    const float* b_hh  = (const float*)d_in[11];
    float* out = (float*)d_out;

    char* ws = (char*)d_ws;
    int*   meta  = (int*)ws;                 // 8 ints
    int*   perm  = (int*)(ws + 256);         // 4096 ints
    float* gates = (float*)(ws + 32768);     // N*2048 f32 = 32 MiB

    build_perm<<<1, 1024, 0, stream>>>(ci, meta, perm);

    dim3 ggrid(NTOK / BM, G4H / BN, MCELL);  // (32, 16, 4); tail blocks exit
    gates_gemm<<<ggrid, 256, 0, stream>>>(x, h, W_ih, W_hh, meta, perm, gates);

    logodds_kernel<<<NTOK, 256, 0, stream>>>(et, cat, W_lin, b_lin, out);

    lstm_epilogue<<<(NTOK * HID) / 256, 256, 0, stream>>>(gates, meta, perm, c, b_ih, b_hh, out);
}

// Round 2
// 274.519 us; speedup vs baseline: 1.7538x; 1.7538x over previous
//
#include <hip/hip_runtime.h>
#include <hip/hip_bf16.h>
#include <stdint.h>

// Problem constants (fixed by the reference)
#define NTOK 4096
#define HID  512
#define INSZ 1024   // E + H
#define KIN  1536   // INSZ + HID (fused LSTM input: x | h)
#define KCAT 64
#define CCH  128
#define MCELL 4
#define G4H  2048   // 4*H

typedef unsigned short u16;
typedef __bf16 bf16x8 __attribute__((ext_vector_type(8)));
typedef float  f32x4  __attribute__((ext_vector_type(4)));

__device__ __forceinline__ u16 f2bf(float f) {
    unsigned u = __float_as_uint(f);
    u += 0x7fffu + ((u >> 16) & 1u);   // RTNE
    return (u16)(u >> 16);
}
__device__ __forceinline__ float bf2f(u16 v) {
    return __uint_as_float(((unsigned)v) << 16);
}
__device__ __forceinline__ void store_bf4(u16* p, float4 v) {
    ushort4 r;
    r.x = f2bf(v.x); r.y = f2bf(v.y); r.z = f2bf(v.z); r.w = f2bf(v.w);
    *reinterpret_cast<ushort4*>(p) = r;
}
__device__ __forceinline__ void gl16(const u16* g, u16* l) {
    // async global->LDS, 16B per lane. LDS dest = wave-uniform base + lane*16.
    __builtin_amdgcn_global_load_lds((const __attribute__((address_space(1))) void*)g,
                                     (__attribute__((address_space(3))) void*)l, 16, 0, 0);
}

// meta layout (ints): [0..3] ci padded cnt, [4..7] ci padded off,
//                     [8..71] cat padded cnt, [72..135] cat padded off
// ---------------------------------------------------------------------------
// Kernel 1: bucket tokens by ci (pad 128) and by cat (pad 64). Order within a
// bucket is atomics-arbitrary — harmless: per-token results don't depend on it.
// ---------------------------------------------------------------------------
__global__ __launch_bounds__(1024) void build_perm(
    const int* __restrict__ ci, const int* __restrict__ cat,
    int* __restrict__ meta, int* __restrict__ perm_ci,
    int* __restrict__ inv_ci, int* __restrict__ perm_cat)
{
    __shared__ int cnt_ci[MCELL], cur_ci[MCELL];
    __shared__ int cnt_cat[KCAT], cur_cat[KCAT];
    int tid = threadIdx.x;
    if (tid < MCELL) cnt_ci[tid] = 0;
    if (tid < KCAT)  cnt_cat[tid] = 0;
    __syncthreads();
    for (int t = tid; t < NTOK; t += 1024) {
        atomicAdd(&cnt_ci[ci[t]], 1);
        atomicAdd(&cnt_cat[cat[t]], 1);
    }
    __syncthreads();
    if (tid == 0) {
        int off = 0;
        for (int m = 0; m < MCELL; ++m) {
            int p = (cnt_ci[m] + 127) & ~127;
            meta[m] = p; meta[4 + m] = off; cur_ci[m] = off; off += p;
        }
        off = 0;
        for (int k = 0; k < KCAT; ++k) {
            int p = (cnt_cat[k] + 63) & ~63;
            meta[8 + k] = p; meta[72 + k] = off; cur_cat[k] = off; off += p;
        }
    }
    __syncthreads();
    for (int i = tid; i < 4608; i += 1024) perm_ci[i] = -1;
    for (int i = tid; i < 8192; i += 1024) perm_cat[i] = -1;
    __syncthreads();
    for (int t = tid; t < NTOK; t += 1024) {
        int s = atomicAdd(&cur_ci[ci[t]], 1);
        perm_ci[s] = t; inv_ci[t] = s;
        int sc = atomicAdd(&cur_cat[cat[t]], 1);
        perm_cat[sc] = t;
    }
}

// ---------------------------------------------------------------------------
// Kernel 2a: pack A = [x|h] rows in ci-slot order, bf16, zero pad rows.
// ---------------------------------------------------------------------------
__global__ __launch_bounds__(192) void pack_A(
    const float* __restrict__ x, const float* __restrict__ h,
    const int* __restrict__ perm_ci, u16* __restrict__ A_pack)
{
    int s = blockIdx.x;
    int c = threadIdx.x * 8;
    int t = perm_ci[s];
    u16* dst = A_pack + (size_t)s * KIN + c;
    if (t < 0) {
        *reinterpret_cast<int4*>(dst) = make_int4(0, 0, 0, 0);
        return;
    }
    const float* src = (c < INSZ) ? (x + (size_t)t * INSZ + c)
                                  : (h + (size_t)t * HID + (c - INSZ));
    float4 v0 = *(const float4*)src;
    float4 v1 = *(const float4*)(src + 4);
    store_bf4(dst, v0);
    store_bf4(dst + 4, v1);
}

// ---------------------------------------------------------------------------
// Kernel 2b: pack W = [W_ih|W_hh] -> [4][2048][1536] bf16.
// ---------------------------------------------------------------------------
__global__ __launch_bounds__(192) void pack_W(
    const float* __restrict__ Wih, const float* __restrict__ Whh,
    u16* __restrict__ Wb)
{
    int row = blockIdx.x;            // m*2048 + j
    int m = row >> 11, j = row & 2047;
    int c = threadIdx.x * 8;
    const float* src = (c < INSZ) ? (Wih + ((size_t)m * G4H + j) * INSZ + c)
                                  : (Whh + ((size_t)m * G4H + j) * HID + (c - INSZ));
    u16* dst = Wb + (size_t)row * KIN + c;
    float4 v0 = *(const float4*)src;
    float4 v1 = *(const float4*)(src + 4);
    store_bf4(dst, v0);
    store_bf4(dst + 4, v1);
}

// ---------------------------------------------------------------------------
// Kernel 3: gates GEMM, m97 structure. 128x128 tile, BK=32, global_load_lds
// width=16, XOR k-block swizzle (2-way bank aliasing = free). Output bf16.
// ---------------------------------------------------------------------------
__global__ __launch_bounds__(256, 2) void gates_gemm(
    const u16* __restrict__ A_pack,   // [4608][1536]
    const u16* __restrict__ Wb,       // [4][2048][1536]
    const int* __restrict__ meta,
    u16* __restrict__ gates)          // [4608][2048] bf16, slot order
{
    int rt = blockIdx.x, ct = blockIdx.y, m = blockIdx.z;
    int pcnt = meta[m];
    if (rt * 128 >= pcnt) return;
    int row0 = meta[4 + m] + rt * 128;

    __shared__ __align__(16) u16 As[128 * 32];
    __shared__ __align__(16) u16 Bs[128 * 32];

    int tid = threadIdx.x;
    int lane = tid & 63, wave = tid >> 6;

    // staging: transfer j = c*256 + tid, r = j>>2 (tile row), cb = j&3 (16B col
    // block). Global source k-block is cb ^ ((r>>1)&3) (bank-deconflict swizzle).
    int r0 = tid >> 2;
    int cb = tid & 3;
    int kcb = cb ^ ((r0 >> 1) & 3);
    const u16* gA0 = A_pack + (size_t)(row0 + r0) * KIN + kcb * 8;
    const u16* gA1 = gA0 + (size_t)64 * KIN;
    const u16* gB0 = Wb + ((size_t)m * G4H + ct * 128 + r0) * KIN + kcb * 8;
    const u16* gB1 = gB0 + (size_t)64 * KIN;
    u16* lA0 = As + wave * 512;          // (wave*64 lanes)*16B
    u16* lA1 = As + 2048 + wave * 512;
    u16* lB0 = Bs + wave * 512;
    u16* lB1 = Bs + 2048 + wave * 512;

    int wr = wave >> 1, wc = wave & 1;
    int qd = lane >> 4, l15 = lane & 15;
    int qs = (qd ^ ((l15 >> 1) & 3)) * 8;   // swizzled k-block (u16 units)

    f32x4 acc[4][4];
    #pragma unroll
    for (int i = 0; i < 4; ++i)
        #pragma unroll
        for (int j = 0; j < 4; ++j)
            acc[i][j] = (f32x4){0.f, 0.f, 0.f, 0.f};

    for (int ks = 0; ks < KIN / 32; ++ks) {
        gl16(gA0, lA0); gl16(gA1, lA1);
        gl16(gB0, lB0); gl16(gB1, lB1);
        gA0 += 32; gA1 += 32; gB0 += 32; gB1 += 32;
        __syncthreads();   // drains vmcnt -> LDS tiles complete

        bf16x8 fa[4], fb[4];
        #pragma unroll
        for (int ti = 0; ti < 4; ++ti)
            fa[ti] = *reinterpret_cast<const bf16x8*>(&As[(wr * 64 + ti * 16 + l15) * 32 + qs]);
        #pragma unroll
        for (int tj = 0; tj < 4; ++tj)
            fb[tj] = *reinterpret_cast<const bf16x8*>(&Bs[(wc * 64 + tj * 16 + l15) * 32 + qs]);
        #pragma unroll
        for (int ti = 0; ti < 4; ++ti)
            #pragma unroll
            for (int tj = 0; tj < 4; ++tj)
                acc[ti][tj] = __builtin_amdgcn_mfma_f32_16x16x32_bf16(fa[ti], fb[tj], acc[ti][tj], 0, 0, 0);
        __syncthreads();
    }

    // C store (bf16). Pad rows are zero-input -> computed but never read.
    #pragma unroll
    for (int ti = 0; ti < 4; ++ti) {
        #pragma unroll
        for (int tj = 0; tj < 4; ++tj) {
            int gcol = ct * 128 + wc * 64 + tj * 16 + l15;
            #pragma unroll
            for (int r = 0; r < 4; ++r) {
                int grow = row0 + wr * 64 + ti * 16 + qd * 4 + r;
                gates[(size_t)grow * G4H + gcol] = f2bf(acc[ti][tj][r]);
            }
        }
    }
}

// ---------------------------------------------------------------------------
// Kernel 4: log_odds — category-bucketed MFMA GEMM. Per (cat, rtile of 64):
// A = et rows (gathered, bf16-converted in staging), B = W_lin[cat] 128x512.
// ---------------------------------------------------------------------------
__global__ __launch_bounds__(256) void logodds_gemm(
    const float* __restrict__ et,     // [N,512]
    const float* __restrict__ W_lin,  // [64,128,512]
    const float* __restrict__ b_lin,  // [64,128]
    const int* __restrict__ meta,
    const int* __restrict__ perm_cat,
    float* __restrict__ out)          // log_odds at out[0 .. N*128)
{
    int k = blockIdx.x, rt = blockIdx.y;
    int pcnt = meta[8 + k];
    if (rt * 64 >= pcnt) return;
    int base = meta[72 + k] + rt * 64;

    __shared__ int srow[64];
    __shared__ __align__(16) u16 As[64 * 40];    // +8 pad per row
    __shared__ __align__(16) u16 Bs[128 * 40];

    int tid = threadIdx.x;
    if (tid < 64) srow[tid] = perm_cat[base + tid];
    __syncthreads();

    int lane = tid & 63, wave = tid >> 6;
    int qd = lane >> 4, l15 = lane & 15;

    f32x4 acc[4][2];
    #pragma unroll
    for (int i = 0; i < 4; ++i) {
        acc[i][0] = (f32x4){0.f, 0.f, 0.f, 0.f};
        acc[i][1] = (f32x4){0.f, 0.f, 0.f, 0.f};
    }

    const float* Wbase = W_lin + (size_t)k * CCH * HID;

    for (int kk = 0; kk < HID; kk += 32) {
        // A staging: 256 tasks (64 rows x 4 col-blocks of 8)
        {
            int r = tid >> 2, cbk = tid & 3;
            u16* dst = &As[r * 40 + cbk * 8];
            int t = srow[r];
            if (t >= 0) {
                const float* s = et + (size_t)t * HID + kk + cbk * 8;
                store_bf4(dst, *(const float4*)s);
                store_bf4(dst + 4, *(const float4*)(s + 4));
            } else {
                *reinterpret_cast<int4*>(dst) = make_int4(0, 0, 0, 0);
            }
        }
        // B staging: 512 tasks
        #pragma unroll
        for (int it = 0; it < 2; ++it) {
            int j = it * 256 + tid;
            int r = j >> 2, cbk = j & 3;
            const float* s = Wbase + (size_t)r * HID + kk + cbk * 8;
            u16* dst = &Bs[r * 40 + cbk * 8];
            store_bf4(dst, *(const float4*)s);
            store_bf4(dst + 4, *(const float4*)(s + 4));
        }
        __syncthreads();

        bf16x8 fa[4], fb[2];
        #pragma unroll
        for (int ti = 0; ti < 4; ++ti)
            fa[ti] = *reinterpret_cast<const bf16x8*>(&As[(ti * 16 + l15) * 40 + qd * 8]);
        #pragma unroll
        for (int tj = 0; tj < 2; ++tj)
            fb[tj] = *reinterpret_cast<const bf16x8*>(&Bs[(wave * 32 + tj * 16 + l15) * 40 + qd * 8]);
        #pragma unroll
        for (int ti = 0; ti < 4; ++ti)
            #pragma unroll
            for (int tj = 0; tj < 2; ++tj)
                acc[ti][tj] = __builtin_amdgcn_mfma_f32_16x16x32_bf16(fa[ti], fb[tj], acc[ti][tj], 0, 0, 0);
        __syncthreads();
    }

    #pragma unroll
    for (int ti = 0; ti < 4; ++ti) {
        #pragma unroll
        for (int tj = 0; tj < 2; ++tj) {
            int n = wave * 32 + tj * 16 + l15;
            #pragma unroll
            for (int r = 0; r < 4; ++r) {
                int row = ti * 16 + qd * 4 + r;
                int t = srow[row];
                if (t >= 0)
                    out[(size_t)t * CCH + n] = acc[ti][tj][r] + b_lin[k * CCH + n];
            }
        }
    }
}

// ---------------------------------------------------------------------------
// Kernel 5: LSTM pointwise epilogue (token-indexed via inverse slot map).
// ---------------------------------------------------------------------------
__global__ __launch_bounds__(256) void lstm_epilogue(
    const u16* __restrict__ gates,    // [4608][2048] bf16, slot order
    const int* __restrict__ meta,
    const int* __restrict__ inv_ci,
    const float* __restrict__ c,
    const float* __restrict__ b_ih,   // [4,2048]
    const float* __restrict__ b_hh,   // [4,2048]
    float* __restrict__ out)
{
    int idx = blockIdx.x * 256 + threadIdx.x;   // [0, N*512)
    int t = idx >> 9;
    int hh = idx & 511;
    int s = inv_ci[t];
    int m = (s >= meta[5]) + (s >= meta[6]) + (s >= meta[7]);

    const u16* g = gates + (size_t)s * G4H;
    const float* bi = b_ih + (size_t)m * G4H;
    const float* bh = b_hh + (size_t)m * G4H;
    float gi = bf2f(g[hh])        + bi[hh]        + bh[hh];
    float gf = bf2f(g[512 + hh])  + bi[512 + hh]  + bh[512 + hh];
    float gg = bf2f(g[1024 + hh]) + bi[1024 + hh] + bh[1024 + hh];
    float go = bf2f(g[1536 + hh]) + bi[1536 + hh] + bh[1536 + hh];

    float si = 1.f / (1.f + __expf(-gi));
    float sf = 1.f / (1.f + __expf(-gf));
    float so = 1.f / (1.f + __expf(-go));
    float ct = c[(size_t)t * HID + hh];
    float c2 = sf * ct + si * tanhf(gg);
    float h2 = so * tanhf(c2);

    const size_t o_h2 = (size_t)NTOK * CCH;
    const size_t o_c2 = o_h2 + (size_t)NTOK * HID;
    out[o_h2 + (size_t)t * HID + hh] = h2;
    out[o_c2 + (size_t)t * HID + hh] = c2;
}

// ---------------------------------------------------------------------------
extern "C" void kernel_launch(void* const* d_in, const int* in_sizes, int n_in,
                              void* d_out, int out_size, void* d_ws, size_t ws_size,
                              hipStream_t stream) {
    const float* et    = (const float*)d_in[0];
    const float* x     = (const float*)d_in[1];
    const float* h     = (const float*)d_in[2];
    const float* c     = (const float*)d_in[3];
    const int*   cat   = (const int*)d_in[4];
    const int*   ci    = (const int*)d_in[5];
    const float* W_lin = (const float*)d_in[6];
    const float* b_lin = (const float*)d_in[7];
    const float* W_ih  = (const float*)d_in[8];
    const float* W_hh  = (const float*)d_in[9];
    const float* b_ih  = (const float*)d_in[10];
    const float* b_hh  = (const float*)d_in[11];
    float* out = (float*)d_out;

    char* ws = (char*)d_ws;
    int* meta     = (int*)ws;                       // 1 KB
    int* perm_ci  = (int*)(ws + 1024);              // 4608 ints
    int* inv_ci   = (int*)(ws + 19456);             // 4096 ints
    int* perm_cat = (int*)(ws + 35840);             // 8192 ints
    u16* A_pack   = (u16*)(ws + 68608);             // 4608*1536*2 = 14155776
    u16* Wb       = (u16*)(ws + 68608 + 14155776);  // 4*2048*1536*2 = 25165824
    u16* gates    = (u16*)(ws + 68608 + 14155776 + 25165824); // 4608*2048*2

    build_perm<<<1, 1024, 0, stream>>>(ci, cat, meta, perm_ci, inv_ci, perm_cat);
    pack_W<<<MCELL * G4H, 192, 0, stream>>>(W_ih, W_hh, Wb);
    pack_A<<<4608, 192, 0, stream>>>(x, h, perm_ci, A_pack);

    dim3 ggrid(36, 16, MCELL);   // 36 row tiles covers any bucket skew; tails exit
    gates_gemm<<<ggrid, 256, 0, stream>>>(A_pack, Wb, meta, gates);

    dim3 lgrid(KCAT, 16);        // 16 row tiles of 64 covers any cat skew
    logodds_gemm<<<lgrid, 256, 0, stream>>>(et, W_lin, b_lin, meta, perm_cat, out);

    lstm_epilogue<<<(NTOK * HID) / 256, 256, 0, stream>>>(gates, meta, inv_ci, c, b_ih, b_hh, out);
}